// Round 1
// baseline (245.506 us; speedup 1.0000x reference)
//
#include <hip/hip_runtime.h>
#include <hip/hip_bf16.h>

#define N_MOL_C 100
#define CUTOFF_F 10.0f
#define SHIFT_F 0.1f           // 1/CUTOFF
#define HALF_KE 7.1998225f     // 0.5 * 14.399645

__global__ __launch_bounds__(256) void EnergyCoulomb_kernel(
    const float* __restrict__ q,
    const float* __restrict__ r_ij,
    const int*   __restrict__ idx_i,
    const int*   __restrict__ idx_j,
    const int*   __restrict__ idx_m,
    float*       __restrict__ out,
    int n_pairs)
{
    __shared__ float smem[N_MOL_C];
    for (int i = threadIdx.x; i < N_MOL_C; i += blockDim.x) smem[i] = 0.0f;
    __syncthreads();

    const int tid    = blockIdx.x * blockDim.x + threadIdx.x;
    const int stride = gridDim.x * blockDim.x;

    for (int p = tid; p < n_pairs; p += stride) {
        const float x = r_ij[3 * p + 0];
        const float y = r_ij[3 * p + 1];
        const float z = r_ij[3 * p + 2];
        const float d2 = x * x + y * y + z * z;
        const float d  = sqrtf(d2);

        const int ai = idx_i[p];
        const int aj = idx_j[p];
        const float qij = q[ai] * q[aj];

        // pot = 1/d + shift^2 * d - 2*shift  (shift^2/(1/d) == shift^2 * d)
        const float inv = 1.0f / d;
        float pot = inv + (SHIFT_F * SHIFT_F) * d - 2.0f * SHIFT_F;
        float val = (d <= CUTOFF_F) ? (qij * pot) : 0.0f;

        const int m = idx_m[ai];          // fuse atom->mol segment sums
        atomicAdd(&smem[m], val);
    }

    __syncthreads();
    for (int i = threadIdx.x; i < N_MOL_C; i += blockDim.x) {
        const float v = smem[i];
        if (v != 0.0f) atomicAdd(&out[i], v * HALF_KE);
    }
}

extern "C" void kernel_launch(void* const* d_in, const int* in_sizes, int n_in,
                              void* d_out, int out_size, void* d_ws, size_t ws_size,
                              hipStream_t stream) {
    const float* q     = (const float*)d_in[0];
    const float* r_ij  = (const float*)d_in[1];
    const int*   idx_i = (const int*)d_in[2];
    const int*   idx_j = (const int*)d_in[3];
    const int*   idx_m = (const int*)d_in[4];
    float* out = (float*)d_out;

    const int n_pairs = in_sizes[2];   // 6,400,000

    // d_out is poisoned with 0xAA before every timed launch — zero it.
    hipMemsetAsync(out, 0, out_size * sizeof(float), stream);

    const int block = 256;
    const int grid  = 2048;            // 524288 threads, ~12 pairs/thread
    EnergyCoulomb_kernel<<<grid, block, 0, stream>>>(
        q, r_ij, idx_i, idx_j, idx_m, out, n_pairs);
}

// Round 2
// 212.782 us; speedup vs baseline: 1.1538x; 1.1538x over previous
//
#include <hip/hip_runtime.h>
#include <hip/hip_bf16.h>

#define N_MOL_C 100
#define CUTOFF2_F 100.0f       // CUTOFF^2
#define SHIFT_F 0.1f           // 1/CUTOFF
#define SHIFT2_F 0.01f         // SHIFT^2
#define HALF_KE 7.1998225f     // 0.5 * 14.399645

__global__ __launch_bounds__(256) void EnergyCoulomb_kernel(
    const float* __restrict__ q,
    const float* __restrict__ r_ij,
    const int*   __restrict__ idx_i,
    const int*   __restrict__ idx_j,
    const int*   __restrict__ idx_m,
    float*       __restrict__ out,
    int n_quads)
{
    __shared__ float smem[N_MOL_C];
    for (int i = threadIdx.x; i < N_MOL_C; i += blockDim.x) smem[i] = 0.0f;
    __syncthreads();

    const int tid    = blockIdx.x * blockDim.x + threadIdx.x;
    const int stride = gridDim.x * blockDim.x;

    const int4*   idx_i4 = (const int4*)idx_i;
    const int4*   idx_j4 = (const int4*)idx_j;
    const float4* r4     = (const float4*)r_ij;

    for (int qid = tid; qid < n_quads; qid += stride) {
        // ---- issue all independent streaming loads up front ----
        const int4 ii = idx_i4[qid];
        const int4 jj = idx_j4[qid];
        const float4 r0 = r4[3 * qid + 0];
        const float4 r1 = r4[3 * qid + 1];
        const float4 r2 = r4[3 * qid + 2];

        // ---- batch the random gathers (8x q, 4x idx_m) ----
        const float qi0 = q[ii.x], qi1 = q[ii.y], qi2 = q[ii.z], qi3 = q[ii.w];
        const float qj0 = q[jj.x], qj1 = q[jj.y], qj2 = q[jj.z], qj3 = q[jj.w];
        const int m0 = idx_m[ii.x];
        const int m1 = idx_m[ii.y];
        const int m2 = idx_m[ii.z];
        const int m3 = idx_m[ii.w];

        // pair 0: (r0.x, r0.y, r0.z)   pair 1: (r0.w, r1.x, r1.y)
        // pair 2: (r1.z, r1.w, r2.x)   pair 3: (r2.y, r2.z, r2.w)
        const float d2_0 = r0.x * r0.x + r0.y * r0.y + r0.z * r0.z;
        const float d2_1 = r0.w * r0.w + r1.x * r1.x + r1.y * r1.y;
        const float d2_2 = r1.z * r1.z + r1.w * r1.w + r2.x * r2.x;
        const float d2_3 = r2.y * r2.y + r2.z * r2.z + r2.w * r2.w;

        // inv = 1/d via rsqrt(d2); d = d2*inv; pot = inv + s^2*d - 2s
        const float inv0 = rsqrtf(d2_0);
        const float inv1 = rsqrtf(d2_1);
        const float inv2 = rsqrtf(d2_2);
        const float inv3 = rsqrtf(d2_3);

        const float pot0 = inv0 + SHIFT2_F * (d2_0 * inv0) - 2.0f * SHIFT_F;
        const float pot1 = inv1 + SHIFT2_F * (d2_1 * inv1) - 2.0f * SHIFT_F;
        const float pot2 = inv2 + SHIFT2_F * (d2_2 * inv2) - 2.0f * SHIFT_F;
        const float pot3 = inv3 + SHIFT2_F * (d2_3 * inv3) - 2.0f * SHIFT_F;

        const float v0 = (d2_0 <= CUTOFF2_F) ? (qi0 * qj0 * pot0) : 0.0f;
        const float v1 = (d2_1 <= CUTOFF2_F) ? (qi1 * qj1 * pot1) : 0.0f;
        const float v2 = (d2_2 <= CUTOFF2_F) ? (qi2 * qj2 * pot2) : 0.0f;
        const float v3 = (d2_3 <= CUTOFF2_F) ? (qi3 * qj3 * pot3) : 0.0f;

        atomicAdd(&smem[m0], v0);
        atomicAdd(&smem[m1], v1);
        atomicAdd(&smem[m2], v2);
        atomicAdd(&smem[m3], v3);
    }

    __syncthreads();
    for (int i = threadIdx.x; i < N_MOL_C; i += blockDim.x) {
        const float v = smem[i];
        if (v != 0.0f) atomicAdd(&out[i], v * HALF_KE);
    }
}

extern "C" void kernel_launch(void* const* d_in, const int* in_sizes, int n_in,
                              void* d_out, int out_size, void* d_ws, size_t ws_size,
                              hipStream_t stream) {
    const float* q     = (const float*)d_in[0];
    const float* r_ij  = (const float*)d_in[1];
    const int*   idx_i = (const int*)d_in[2];
    const int*   idx_j = (const int*)d_in[3];
    const int*   idx_m = (const int*)d_in[4];
    float* out = (float*)d_out;

    const int n_pairs = in_sizes[2];   // 6,400,000 (divisible by 4)
    const int n_quads = n_pairs >> 2;  // 1,600,000

    // d_out is poisoned with 0xAA before every timed launch — zero it.
    hipMemsetAsync(out, 0, out_size * sizeof(float), stream);

    const int block = 256;
    const int grid  = 2048;            // 524288 threads, ~3 quads/thread
    EnergyCoulomb_kernel<<<grid, block, 0, stream>>>(
        q, r_ij, idx_i, idx_j, idx_m, out, n_quads);
}

// Round 3
// 201.385 us; speedup vs baseline: 1.2191x; 1.0566x over previous
//
#include <hip/hip_runtime.h>
#include <hip/hip_bf16.h>

#define N_MOL_C 100
#define N_ATOMS_C 100000
#define CUTOFF2_F 100.0f       // CUTOFF^2
#define SHIFT_F 0.1f           // 1/CUTOFF
#define SHIFT2_F 0.01f         // SHIFT^2
#define HALF_KE 7.1998225f     // 0.5 * 14.399645

#define MAIN_BLOCK 256
#define NBLK_MAIN 6250         // 6.4M pairs / 4 per thread / 256 threads

// ---------- prologue: pack {q[a], idx_m[a]} into interleaved float2 ----------
__global__ __launch_bounds__(256) void pack_qm_kernel(
    const float* __restrict__ q,
    const int*   __restrict__ idx_m,
    float2*      __restrict__ qm,
    int n_atoms)
{
    int a = blockIdx.x * blockDim.x + threadIdx.x;
    if (a < n_atoms) {
        float2 v;
        v.x = q[a];
        v.y = __int_as_float(idx_m[a]);
        qm[a] = v;
    }
}

// ---------- main: one quad of pairs per thread, partials to ws ----------
__global__ __launch_bounds__(MAIN_BLOCK) void coulomb_main_kernel(
    const float*  __restrict__ q,
    const float2* __restrict__ qm,
    const float*  __restrict__ r_ij,
    const int*    __restrict__ idx_i,
    const int*    __restrict__ idx_j,
    float*        __restrict__ partials)   // [N_MOL_C * NBLK_MAIN]
{
    __shared__ float smem[N_MOL_C];
    for (int i = threadIdx.x; i < N_MOL_C; i += MAIN_BLOCK) smem[i] = 0.0f;
    __syncthreads();

    const int qid = blockIdx.x * MAIN_BLOCK + threadIdx.x;  // quad id, always < n_quads

    // ---- streaming loads (coalesced, wide) ----
    const int4 ii   = ((const int4*)idx_i)[qid];
    const int4 jj   = ((const int4*)idx_j)[qid];
    const float4 r0 = ((const float4*)r_ij)[3 * qid + 0];
    const float4 r1 = ((const float4*)r_ij)[3 * qid + 1];
    const float4 r2 = ((const float4*)r_ij)[3 * qid + 2];

    // ---- gathers: 4x dwordx2 (q_i + mol) + 4x dword (q_j) ----
    const float2 qm0 = qm[ii.x];
    const float2 qm1 = qm[ii.y];
    const float2 qm2 = qm[ii.z];
    const float2 qm3 = qm[ii.w];
    const float qj0 = q[jj.x], qj1 = q[jj.y], qj2 = q[jj.z], qj3 = q[jj.w];

    const float d2_0 = r0.x * r0.x + r0.y * r0.y + r0.z * r0.z;
    const float d2_1 = r0.w * r0.w + r1.x * r1.x + r1.y * r1.y;
    const float d2_2 = r1.z * r1.z + r1.w * r1.w + r2.x * r2.x;
    const float d2_3 = r2.y * r2.y + r2.z * r2.z + r2.w * r2.w;

    const float inv0 = rsqrtf(d2_0);
    const float inv1 = rsqrtf(d2_1);
    const float inv2 = rsqrtf(d2_2);
    const float inv3 = rsqrtf(d2_3);

    const float pot0 = inv0 + SHIFT2_F * (d2_0 * inv0) - 2.0f * SHIFT_F;
    const float pot1 = inv1 + SHIFT2_F * (d2_1 * inv1) - 2.0f * SHIFT_F;
    const float pot2 = inv2 + SHIFT2_F * (d2_2 * inv2) - 2.0f * SHIFT_F;
    const float pot3 = inv3 + SHIFT2_F * (d2_3 * inv3) - 2.0f * SHIFT_F;

    const float v0 = (d2_0 <= CUTOFF2_F) ? (qm0.x * qj0 * pot0) : 0.0f;
    const float v1 = (d2_1 <= CUTOFF2_F) ? (qm1.x * qj1 * pot1) : 0.0f;
    const float v2 = (d2_2 <= CUTOFF2_F) ? (qm2.x * qj2 * pot2) : 0.0f;
    const float v3 = (d2_3 <= CUTOFF2_F) ? (qm3.x * qj3 * pot3) : 0.0f;

    atomicAdd(&smem[__float_as_int(qm0.y)], v0);
    atomicAdd(&smem[__float_as_int(qm1.y)], v1);
    atomicAdd(&smem[__float_as_int(qm2.y)], v2);
    atomicAdd(&smem[__float_as_int(qm3.y)], v3);

    __syncthreads();
    // plain stores of per-block partials: partials[m * NBLK_MAIN + block]
    for (int m = threadIdx.x; m < N_MOL_C; m += MAIN_BLOCK)
        partials[m * NBLK_MAIN + blockIdx.x] = smem[m];
}

// ---------- epilogue: reduce partials -> out, scale ----------
__global__ __launch_bounds__(256) void reduce_kernel(
    const float* __restrict__ partials,
    float*       __restrict__ out)
{
    const int m = blockIdx.x;          // 100 blocks, one per molecule
    const float* col = partials + (size_t)m * NBLK_MAIN;

    float s = 0.0f;
    for (int k = threadIdx.x; k < NBLK_MAIN; k += 256) s += col[k];

    // wave reduce (64 lanes)
    #pragma unroll
    for (int off = 32; off > 0; off >>= 1) s += __shfl_down(s, off, 64);

    __shared__ float wsum[4];
    const int wave = threadIdx.x >> 6;
    const int lane = threadIdx.x & 63;
    if (lane == 0) wsum[wave] = s;
    __syncthreads();
    if (threadIdx.x == 0)
        out[m] = HALF_KE * (wsum[0] + wsum[1] + wsum[2] + wsum[3]);
}

// ---------- fallback (R1 path) if ws too small ----------
__global__ __launch_bounds__(256) void coulomb_fallback_kernel(
    const float* __restrict__ q,
    const float* __restrict__ r_ij,
    const int*   __restrict__ idx_i,
    const int*   __restrict__ idx_j,
    const int*   __restrict__ idx_m,
    float*       __restrict__ out,
    int n_quads)
{
    __shared__ float smem[N_MOL_C];
    for (int i = threadIdx.x; i < N_MOL_C; i += blockDim.x) smem[i] = 0.0f;
    __syncthreads();

    const int tid    = blockIdx.x * blockDim.x + threadIdx.x;
    const int stride = gridDim.x * blockDim.x;

    for (int qid = tid; qid < n_quads; qid += stride) {
        const int4 ii = ((const int4*)idx_i)[qid];
        const int4 jj = ((const int4*)idx_j)[qid];
        const float4 r0 = ((const float4*)r_ij)[3 * qid + 0];
        const float4 r1 = ((const float4*)r_ij)[3 * qid + 1];
        const float4 r2 = ((const float4*)r_ij)[3 * qid + 2];

        const float qi0 = q[ii.x], qi1 = q[ii.y], qi2 = q[ii.z], qi3 = q[ii.w];
        const float qj0 = q[jj.x], qj1 = q[jj.y], qj2 = q[jj.z], qj3 = q[jj.w];
        const int m0 = idx_m[ii.x], m1 = idx_m[ii.y], m2 = idx_m[ii.z], m3 = idx_m[ii.w];

        const float d2_0 = r0.x * r0.x + r0.y * r0.y + r0.z * r0.z;
        const float d2_1 = r0.w * r0.w + r1.x * r1.x + r1.y * r1.y;
        const float d2_2 = r1.z * r1.z + r1.w * r1.w + r2.x * r2.x;
        const float d2_3 = r2.y * r2.y + r2.z * r2.z + r2.w * r2.w;

        const float inv0 = rsqrtf(d2_0), inv1 = rsqrtf(d2_1);
        const float inv2 = rsqrtf(d2_2), inv3 = rsqrtf(d2_3);

        const float pot0 = inv0 + SHIFT2_F * (d2_0 * inv0) - 2.0f * SHIFT_F;
        const float pot1 = inv1 + SHIFT2_F * (d2_1 * inv1) - 2.0f * SHIFT_F;
        const float pot2 = inv2 + SHIFT2_F * (d2_2 * inv2) - 2.0f * SHIFT_F;
        const float pot3 = inv3 + SHIFT2_F * (d2_3 * inv3) - 2.0f * SHIFT_F;

        atomicAdd(&smem[m0], (d2_0 <= CUTOFF2_F) ? (qi0 * qj0 * pot0) : 0.0f);
        atomicAdd(&smem[m1], (d2_1 <= CUTOFF2_F) ? (qi1 * qj1 * pot1) : 0.0f);
        atomicAdd(&smem[m2], (d2_2 <= CUTOFF2_F) ? (qi2 * qj2 * pot2) : 0.0f);
        atomicAdd(&smem[m3], (d2_3 <= CUTOFF2_F) ? (qi3 * qj3 * pot3) : 0.0f);
    }

    __syncthreads();
    for (int i = threadIdx.x; i < N_MOL_C; i += blockDim.x) {
        const float v = smem[i];
        if (v != 0.0f) atomicAdd(&out[i], v * HALF_KE);
    }
}

extern "C" void kernel_launch(void* const* d_in, const int* in_sizes, int n_in,
                              void* d_out, int out_size, void* d_ws, size_t ws_size,
                              hipStream_t stream) {
    const float* q     = (const float*)d_in[0];
    const float* r_ij  = (const float*)d_in[1];
    const int*   idx_i = (const int*)d_in[2];
    const int*   idx_j = (const int*)d_in[3];
    const int*   idx_m = (const int*)d_in[4];
    float* out = (float*)d_out;

    const int n_pairs = in_sizes[2];   // 6,400,000
    const int n_atoms = in_sizes[0];   // 100,000

    // ws layout: [qm table: n_atoms float2][partials: N_MOL_C * NBLK_MAIN floats]
    const size_t qm_bytes   = (size_t)n_atoms * sizeof(float2);
    const size_t part_bytes = (size_t)N_MOL_C * NBLK_MAIN * sizeof(float);
    const size_t need = qm_bytes + part_bytes;

    if (ws_size >= need && n_pairs == NBLK_MAIN * MAIN_BLOCK * 4) {
        float2* qm      = (float2*)d_ws;
        float*  partials = (float*)((char*)d_ws + qm_bytes);

        pack_qm_kernel<<<(n_atoms + 255) / 256, 256, 0, stream>>>(q, idx_m, qm, n_atoms);
        coulomb_main_kernel<<<NBLK_MAIN, MAIN_BLOCK, 0, stream>>>(
            q, qm, r_ij, idx_i, idx_j, partials);
        reduce_kernel<<<N_MOL_C, 256, 0, stream>>>(partials, out);
    } else {
        hipMemsetAsync(out, 0, out_size * sizeof(float), stream);
        coulomb_fallback_kernel<<<2048, 256, 0, stream>>>(
            q, r_ij, idx_i, idx_j, idx_m, out, n_pairs >> 2);
    }
}